// Round 1
// baseline (751.404 us; speedup 1.0000x reference)
//
#include <hip/hip_runtime.h>
#include <hip/hip_bf16.h>
#include <stdint.h>

// Problem constants (fixed by the reference): B=8,S=1024,D=1024,E=8,H=4096,top_k=2
#define TKN   8192              // B*S tokens
#define DD    1024
#define EE    8
#define HH    4096
#define TOPK  2
#define NASG  (TKN * TOPK)      // 16384 assignments

typedef unsigned short u16;
typedef __bf16 bf16x8 __attribute__((ext_vector_type(8)));
typedef float  f32x4  __attribute__((ext_vector_type(4)));

__device__ __forceinline__ u16 f2bf(float f) {
  __hip_bfloat16 h = __float2bfloat16(f);
  return __builtin_bit_cast(u16, h);
}

// async global->LDS, 16B per lane; LDS dest is wave-uniform base + lane*16
__device__ __forceinline__ void glds16(const void* g, void* l) {
  __builtin_amdgcn_global_load_lds(
      (__attribute__((address_space(1))) void*)g,
      (__attribute__((address_space(3))) void*)l, 16, 0, 0);
}

// ---------------- transpose + f32->bf16 convert: [E][R][C] f32 -> [E][C][R] bf16
__global__ __launch_bounds__(256) void transpose_cvt_kernel(
    const float* __restrict__ src, u16* __restrict__ dst, int R, int C) {
  __shared__ float tile[32][33];
  int e = blockIdx.z;
  int c0 = blockIdx.x * 32, r0 = blockIdx.y * 32;
  int tx = threadIdx.x, ty = threadIdx.y;  // 32 x 8
  const float* s = src + (size_t)e * R * C;
  u16* d = dst + (size_t)e * R * C;
#pragma unroll
  for (int j = 0; j < 4; j++)
    tile[ty * 4 + j][tx] = s[(size_t)(r0 + ty * 4 + j) * C + c0 + tx];
  __syncthreads();
#pragma unroll
  for (int j = 0; j < 4; j++)
    d[(size_t)(c0 + ty * 4 + j) * R + r0 + tx] = f2bf(tile[tx][ty * 4 + j]);
}

// ---------------- router: 16 fp32 dots per token, noisy top-2, gating; also x->bf16
__global__ __launch_bounds__(256) void router_kernel(
    const float* __restrict__ x, const float* __restrict__ noise,
    const float* __restrict__ Wg, const float* __restrict__ bg,
    const float* __restrict__ Wn, const float* __restrict__ bn,
    float* __restrict__ gating, u16* __restrict__ xb,
    int* __restrict__ sel_e, float* __restrict__ sel_g) {
  int t = blockIdx.x;
  int tid = threadIdx.x;
  float acc[16];
#pragma unroll
  for (int j = 0; j < 16; j++) acc[j] = 0.f;
  for (int i = tid; i < DD; i += 256) {
    float xv = x[(size_t)t * DD + i];
    xb[(size_t)t * DD + i] = f2bf(xv);
    const float4* g4 = (const float4*)(Wg + (size_t)i * EE);
    const float4* n4 = (const float4*)(Wn + (size_t)i * EE);
    float4 ga = g4[0], gb = g4[1];
    float4 na = n4[0], nb = n4[1];
    acc[0] += xv * ga.x;  acc[1] += xv * ga.y;  acc[2] += xv * ga.z;  acc[3] += xv * ga.w;
    acc[4] += xv * gb.x;  acc[5] += xv * gb.y;  acc[6] += xv * gb.z;  acc[7] += xv * gb.w;
    acc[8] += xv * na.x;  acc[9] += xv * na.y;  acc[10] += xv * na.z; acc[11] += xv * na.w;
    acc[12] += xv * nb.x; acc[13] += xv * nb.y; acc[14] += xv * nb.z; acc[15] += xv * nb.w;
  }
  __shared__ float red[4][16];
  int lane = tid & 63, wv = tid >> 6;
#pragma unroll
  for (int j = 0; j < 16; j++) {
    float v = acc[j];
    for (int o = 32; o > 0; o >>= 1) v += __shfl_down(v, o);
    acc[j] = v;
  }
  if (lane == 0) {
#pragma unroll
    for (int j = 0; j < 16; j++) red[wv][j] = acc[j];
  }
  __syncthreads();
  if (tid == 0) {
    float nz[EE];
#pragma unroll
    for (int e = 0; e < EE; e++) {
      float dg = red[0][e] + red[1][e] + red[2][e] + red[3][e] + bg[e];
      float dn = red[0][8 + e] + red[1][8 + e] + red[2][8 + e] + red[3][8 + e] + bn[e];
      // stable softplus, matches jax.nn.softplus = logaddexp(x,0)
      float sp = fmaxf(dn, 0.f) + log1pf(expf(-fabsf(dn)));
      nz[e] = dg + noise[(size_t)t * EE + e] * sp;
    }
    // top-2 with jax.lax.top_k tie semantics (lowest index first)
    int m1 = 0;
    for (int e = 1; e < EE; e++) if (nz[e] > nz[m1]) m1 = e;
    int m2 = (m1 == 0) ? 1 : 0;
    for (int e = 0; e < EE; e++) if (e != m1 && nz[e] > nz[m2]) m2 = e;
    float eb = expf(nz[m2] - nz[m1]);  // <= 1
    float den = 1.f + eb;
    float g1 = 1.f / den, g2 = eb / den;
    gating[(size_t)t * EE + m1] = g1;
    gating[(size_t)t * EE + m2] = g2;
    sel_e[t * 2] = m1; sel_e[t * 2 + 1] = m2;
    sel_g[t * 2] = g1; sel_g[t * 2 + 1] = g2;
  }
}

// ---------------- histogram + exclusive scan (1 block)
__global__ __launch_bounds__(256) void hist_scan_kernel(
    const int* __restrict__ sel_e, int* __restrict__ counts,
    int* __restrict__ offsets, int* __restrict__ cursors) {
  __shared__ int hist[EE];
  int tid = threadIdx.x;
  if (tid < EE) hist[tid] = 0;
  __syncthreads();
  for (int i = tid; i < NASG; i += 256) atomicAdd(&hist[sel_e[i]], 1);
  __syncthreads();
  if (tid == 0) {
    int off = 0;
    for (int e = 0; e < EE; e++) {
      counts[e] = hist[e]; offsets[e] = off; cursors[e] = off; off += hist[e];
    }
  }
}

// ---------------- build per-expert token lists (ballot-aggregated atomics)
__global__ __launch_bounds__(256) void build_lists_kernel(
    const int* __restrict__ sel_e, const float* __restrict__ sel_g,
    int* __restrict__ cursors, int* __restrict__ tok_list,
    float* __restrict__ gate_list) {
  int t = blockIdx.x * 256 + threadIdx.x;  // exact grid: 8192 threads
  int lane = threadIdx.x & 63;
#pragma unroll
  for (int k = 0; k < TOPK; k++) {
    int e = sel_e[t * 2 + k];
    float g = sel_g[t * 2 + k];
    for (int ee = 0; ee < EE; ee++) {
      unsigned long long m = __ballot(e == ee);
      if (m) {
        int leader = __ffsll(m) - 1;
        int base = 0;
        if (lane == leader) base = atomicAdd(&cursors[ee], __popcll(m));
        base = __shfl(base, leader);
        if (e == ee) {
          int slot = base + __popcll(m & ((1ull << lane) - 1ull));
          tok_list[slot] = t;
          gate_list[slot] = g;
        }
      }
    }
  }
}

// ---------------- grouped GEMM1: h = relu(x[tok] @ W1[e] + b1[e]), bf16 out
// A: gathered rows of xb [*][1024]; B: w1t [E][H][D] (n-major); C rows = assignment slots
__global__ __launch_bounds__(256) void gemm1_kernel(
    const u16* __restrict__ xb, const u16* __restrict__ w1t,
    const float* __restrict__ b1, const int* __restrict__ tok_list,
    const int* __restrict__ counts, const int* __restrict__ offsets,
    u16* __restrict__ h) {
  int e = blockIdx.z;
  int cnt = counts[e];
  int rt = blockIdx.y;
  if (rt * 128 >= cnt) return;
  int off = offsets[e];
  int col0 = blockIdx.x * 128;
  __shared__ __attribute__((aligned(16))) u16 As[128 * 32];
  __shared__ __attribute__((aligned(16))) u16 Bs[128 * 32];
  int tid = threadIdx.x, lane = tid & 63, wv = tid >> 6;
  int rquart = tid >> 2;          // local row 0..63 (iter0), +64 (iter1)
  int kl = (tid & 3) * 8;         // k element offset within 32-wide K tile
  int tokA0 = tok_list[min(off + rt * 128 + rquart, NASG - 1)];
  int tokA1 = tok_list[min(off + rt * 128 + rquart + 64, NASG - 1)];
  const u16* a0p = xb + (size_t)tokA0 * DD + kl;
  const u16* a1p = xb + (size_t)tokA1 * DD + kl;
  const u16* b0p = w1t + ((size_t)e * HH + col0 + rquart) * DD + kl;
  const u16* b1p = b0p + (size_t)64 * DD;
  u16* As0 = &As[wv * 512];       u16* As1 = &As[(4 + wv) * 512];
  u16* Bs0 = &Bs[wv * 512];       u16* Bs1 = &Bs[(4 + wv) * 512];
  f32x4 acc[4][4];
#pragma unroll
  for (int m = 0; m < 4; m++)
#pragma unroll
    for (int n = 0; n < 4; n++) acc[m][n] = (f32x4){0.f, 0.f, 0.f, 0.f};
  int wr = (wv >> 1) * 64, wc = (wv & 1) * 64;
  int fr = lane & 15, kk = (lane >> 4) * 8, hi = lane >> 4;

  for (int k0 = 0; k0 < DD; k0 += 32) {
    glds16(a0p + k0, As0);
    glds16(a1p + k0, As1);
    glds16(b0p + k0, Bs0);
    glds16(b1p + k0, Bs1);
    __syncthreads();
    bf16x8 af[4], bfv[4];
#pragma unroll
    for (int m = 0; m < 4; m++)
      af[m] = *(const bf16x8*)&As[(wr + m * 16 + fr) * 32 + kk];
#pragma unroll
    for (int n = 0; n < 4; n++)
      bfv[n] = *(const bf16x8*)&Bs[(wc + n * 16 + fr) * 32 + kk];
#pragma unroll
    for (int m = 0; m < 4; m++)
#pragma unroll
      for (int n = 0; n < 4; n++)
        acc[m][n] = __builtin_amdgcn_mfma_f32_16x16x32_bf16(af[m], bfv[n], acc[m][n], 0, 0, 0);
    __syncthreads();
  }
  // epilogue: + b1, relu, store bf16
#pragma unroll
  for (int n = 0; n < 4; n++) {
    int c = col0 + wc + n * 16 + fr;
    float bias = b1[e * HH + c];
#pragma unroll
    for (int m = 0; m < 4; m++) {
      int rbase = rt * 128 + wr + m * 16 + hi * 4;
#pragma unroll
      for (int j = 0; j < 4; j++) {
        int r = rbase + j;
        if (r < cnt) {
          float v = acc[m][n][j] + bias;
          h[(size_t)(off + r) * HH + c] = f2bf(fmaxf(v, 0.f));
        }
      }
    }
  }
}

// ---------------- grouped GEMM2: y = (h @ W2[e] + b2[e]) * gate; scatter + reduce
__global__ __launch_bounds__(256) void gemm2_kernel(
    const u16* __restrict__ h, const u16* __restrict__ w2t,
    const float* __restrict__ b2, const int* __restrict__ tok_list,
    const float* __restrict__ gate_list, const int* __restrict__ counts,
    const int* __restrict__ offsets, float* __restrict__ final_out,
    float* __restrict__ expert_out) {
  int e = blockIdx.z;
  int cnt = counts[e];
  int rt = blockIdx.y;
  if (rt * 128 >= cnt) return;
  int off = offsets[e];
  int col0 = blockIdx.x * 128;
  __shared__ __attribute__((aligned(16))) u16 As[128 * 32];
  __shared__ __attribute__((aligned(16))) u16 Bs[128 * 32];
  int tid = threadIdx.x, lane = tid & 63, wv = tid >> 6;
  int rquart = tid >> 2;
  int kl = (tid & 3) * 8;
  const u16* a0p = h + (size_t)(off + rt * 128 + rquart) * HH + kl;  // rows contiguous
  const u16* a1p = a0p + (size_t)64 * HH;
  const u16* b0p = w2t + ((size_t)e * DD + col0 + rquart) * HH + kl;
  const u16* b1p = b0p + (size_t)64 * HH;
  u16* As0 = &As[wv * 512];       u16* As1 = &As[(4 + wv) * 512];
  u16* Bs0 = &Bs[wv * 512];       u16* Bs1 = &Bs[(4 + wv) * 512];
  f32x4 acc[4][4];
#pragma unroll
  for (int m = 0; m < 4; m++)
#pragma unroll
    for (int n = 0; n < 4; n++) acc[m][n] = (f32x4){0.f, 0.f, 0.f, 0.f};
  int wr = (wv >> 1) * 64, wc = (wv & 1) * 64;
  int fr = lane & 15, kk = (lane >> 4) * 8, hi = lane >> 4;

  for (int k0 = 0; k0 < HH; k0 += 32) {
    glds16(a0p + k0, As0);
    glds16(a1p + k0, As1);
    glds16(b0p + k0, Bs0);
    glds16(b1p + k0, Bs1);
    __syncthreads();
    bf16x8 af[4], bfv[4];
#pragma unroll
    for (int m = 0; m < 4; m++)
      af[m] = *(const bf16x8*)&As[(wr + m * 16 + fr) * 32 + kk];
#pragma unroll
    for (int n = 0; n < 4; n++)
      bfv[n] = *(const bf16x8*)&Bs[(wc + n * 16 + fr) * 32 + kk];
#pragma unroll
    for (int m = 0; m < 4; m++)
#pragma unroll
      for (int n = 0; n < 4; n++)
        acc[m][n] = __builtin_amdgcn_mfma_f32_16x16x32_bf16(af[m], bfv[n], acc[m][n], 0, 0, 0);
    __syncthreads();
  }
  // epilogue: + b2, * gate, scatter to expert_out, atomic-accumulate final
  int cN[4]; float biasN[4];
#pragma unroll
  for (int n = 0; n < 4; n++) {
    cN[n] = col0 + wc + n * 16 + fr;
    biasN[n] = b2[e * DD + cN[n]];
  }
#pragma unroll
  for (int m = 0; m < 4; m++) {
    int rbase = rt * 128 + wr + m * 16 + hi * 4;
#pragma unroll
    for (int j = 0; j < 4; j++) {
      int r = rbase + j;
      if (r < cnt) {
        int idx = off + r;
        int tok = tok_list[idx];
        float g = gate_list[idx];
        size_t erow = ((size_t)e * TKN + tok) * DD;
        size_t frow = (size_t)tok * DD;
#pragma unroll
        for (int n = 0; n < 4; n++) {
          float val = (acc[m][n][j] + biasN[n]) * g;
          expert_out[erow + cN[n]] = val;
          atomicAdd(&final_out[frow + cN[n]], val);
        }
      }
    }
  }
}

extern "C" void kernel_launch(void* const* d_in, const int* in_sizes, int n_in,
                              void* d_out, int out_size, void* d_ws, size_t ws_size,
                              hipStream_t stream) {
  const float* x     = (const float*)d_in[0];
  const float* noise = (const float*)d_in[1];
  const float* Wg    = (const float*)d_in[2];
  const float* bg    = (const float*)d_in[3];
  const float* Wn    = (const float*)d_in[4];
  const float* bn    = (const float*)d_in[5];
  const float* W1    = (const float*)d_in[6];
  const float* b1    = (const float*)d_in[7];
  const float* W2    = (const float*)d_in[8];
  const float* b2    = (const float*)d_in[9];

  float* final_out  = (float*)d_out;
  float* expert_out = final_out + (size_t)TKN * DD;
  float* gating     = expert_out + (size_t)EE * TKN * DD;

  // workspace layout (~287 MB total)
  char* ws = (char*)d_ws;
  size_t o = 0;
  auto alloc = [&](size_t bytes) {
    char* p = ws + o;
    o += bytes;
    o = (o + 255) & ~(size_t)255;
    return p;
  };
  u16*   xb        = (u16*)alloc((size_t)TKN * DD * 2);            // 16.8 MB
  u16*   w1t       = (u16*)alloc((size_t)EE * HH * DD * 2);        // 67 MB [E][H][D]
  u16*   w2t       = (u16*)alloc((size_t)EE * DD * HH * 2);        // 67 MB [E][D][H]
  u16*   hbuf      = (u16*)alloc(((size_t)NASG + 128) * HH * 2);   // 135 MB (+pad rows)
  int*   tok_list  = (int*)alloc((size_t)NASG * 4);
  float* gate_list = (float*)alloc((size_t)NASG * 4);
  int*   sel_e     = (int*)alloc((size_t)NASG * 4);
  float* sel_g     = (float*)alloc((size_t)NASG * 4);
  int*   counts    = (int*)alloc(256);
  int*   offsets   = (int*)alloc(256);
  int*   cursors   = (int*)alloc(256);

  // zero all outputs (non-selected expert rows / gating zeros; final for atomics)
  hipMemsetAsync(d_out, 0, (size_t)out_size * sizeof(float), stream);

  // weights -> bf16, n-major
  transpose_cvt_kernel<<<dim3(HH / 32, DD / 32, EE), dim3(32, 8), 0, stream>>>(W1, w1t, DD, HH);
  transpose_cvt_kernel<<<dim3(DD / 32, HH / 32, EE), dim3(32, 8), 0, stream>>>(W2, w2t, HH, DD);

  router_kernel<<<TKN, 256, 0, stream>>>(x, noise, Wg, bg, Wn, bn, gating, xb, sel_e, sel_g);
  hist_scan_kernel<<<1, 256, 0, stream>>>(sel_e, counts, offsets, cursors);
  build_lists_kernel<<<TKN / 256, 256, 0, stream>>>(sel_e, sel_g, cursors, tok_list, gate_list);

  gemm1_kernel<<<dim3(HH / 128, 64, EE), 256, 0, stream>>>(xb, w1t, b1, tok_list, counts, offsets, hbuf);
  gemm2_kernel<<<dim3(DD / 128, 64, EE), 256, 0, stream>>>(hbuf, w2t, b2, tok_list, gate_list,
                                                           counts, offsets, final_out, expert_out);
}

// Round 3
// 654.602 us; speedup vs baseline: 1.1479x; 1.1479x over previous
//
#include <hip/hip_runtime.h>
#include <hip/hip_bf16.h>
#include <stdint.h>

// Problem constants: B=8,S=1024,D=1024,E=8,H=4096,top_k=2
#define TKN   8192
#define DD    1024
#define EE    8
#define HH    4096
#define TOPK  2
#define NASG  (TKN * TOPK)      // 16384 assignments

typedef unsigned short u16;
typedef __bf16 bf16x8 __attribute__((ext_vector_type(8)));
typedef float  f32x4  __attribute__((ext_vector_type(4)));

__device__ __forceinline__ u16 f2bf(float f) {
  __hip_bfloat16 h = __float2bfloat16(f);
  return __builtin_bit_cast(u16, h);
}

__device__ __forceinline__ void glds16(const void* g, void* l) {
  __builtin_amdgcn_global_load_lds(
      (__attribute__((address_space(1))) void*)g,
      (__attribute__((address_space(3))) void*)l, 16, 0, 0);
}

#define FENCE() asm volatile("" ::: "memory")
#define BAR()   do { FENCE(); __builtin_amdgcn_s_barrier(); FENCE(); } while (0)
#define VMCNT4() asm volatile("s_waitcnt vmcnt(4)" ::: "memory")
#define VMCNT0() asm volatile("s_waitcnt vmcnt(0)" ::: "memory")

// ---------------- transpose + f32->bf16 convert: [E][R][C] f32 -> [E][C][R] bf16
__global__ __launch_bounds__(256) void transpose_cvt_kernel(
    const float* __restrict__ src, u16* __restrict__ dst, int R, int C) {
  __shared__ float tile[32][33];
  int e = blockIdx.z;
  int c0 = blockIdx.x * 32, r0 = blockIdx.y * 32;
  int tx = threadIdx.x, ty = threadIdx.y;  // 32 x 8
  const float* s = src + (size_t)e * R * C;
  u16* d = dst + (size_t)e * R * C;
#pragma unroll
  for (int j = 0; j < 4; j++)
    tile[ty * 4 + j][tx] = s[(size_t)(r0 + ty * 4 + j) * C + c0 + tx];
  __syncthreads();
#pragma unroll
  for (int j = 0; j < 4; j++)
    d[(size_t)(c0 + ty * 4 + j) * R + r0 + tx] = f2bf(tile[tx][ty * 4 + j]);
}

// ---------------- router
__global__ __launch_bounds__(256) void router_kernel(
    const float* __restrict__ x, const float* __restrict__ noise,
    const float* __restrict__ Wg, const float* __restrict__ bg,
    const float* __restrict__ Wn, const float* __restrict__ bn,
    float* __restrict__ gating, u16* __restrict__ xb,
    int* __restrict__ sel_e, float* __restrict__ sel_g) {
  int t = blockIdx.x;
  int tid = threadIdx.x;
  float acc[16];
#pragma unroll
  for (int j = 0; j < 16; j++) acc[j] = 0.f;
  for (int i = tid; i < DD; i += 256) {
    float xv = x[(size_t)t * DD + i];
    xb[(size_t)t * DD + i] = f2bf(xv);
    const float4* g4 = (const float4*)(Wg + (size_t)i * EE);
    const float4* n4 = (const float4*)(Wn + (size_t)i * EE);
    float4 ga = g4[0], gb = g4[1];
    float4 na = n4[0], nb = n4[1];
    acc[0] += xv * ga.x;  acc[1] += xv * ga.y;  acc[2] += xv * ga.z;  acc[3] += xv * ga.w;
    acc[4] += xv * gb.x;  acc[5] += xv * gb.y;  acc[6] += xv * gb.z;  acc[7] += xv * gb.w;
    acc[8] += xv * na.x;  acc[9] += xv * na.y;  acc[10] += xv * na.z; acc[11] += xv * na.w;
    acc[12] += xv * nb.x; acc[13] += xv * nb.y; acc[14] += xv * nb.z; acc[15] += xv * nb.w;
  }
  __shared__ float red[4][16];
  int lane = tid & 63, wv = tid >> 6;
#pragma unroll
  for (int j = 0; j < 16; j++) {
    float v = acc[j];
    for (int o = 32; o > 0; o >>= 1) v += __shfl_down(v, o);
    acc[j] = v;
  }
  if (lane == 0) {
#pragma unroll
    for (int j = 0; j < 16; j++) red[wv][j] = acc[j];
  }
  __syncthreads();
  if (tid == 0) {
    float nz[EE];
#pragma unroll
    for (int e = 0; e < EE; e++) {
      float dg = red[0][e] + red[1][e] + red[2][e] + red[3][e] + bg[e];
      float dn = red[0][8 + e] + red[1][8 + e] + red[2][8 + e] + red[3][8 + e] + bn[e];
      float sp = fmaxf(dn, 0.f) + log1pf(expf(-fabsf(dn)));
      nz[e] = dg + noise[(size_t)t * EE + e] * sp;
    }
    int m1 = 0;
    for (int e = 1; e < EE; e++) if (nz[e] > nz[m1]) m1 = e;
    int m2 = (m1 == 0) ? 1 : 0;
    for (int e = 0; e < EE; e++) if (e != m1 && nz[e] > nz[m2]) m2 = e;
    float eb = expf(nz[m2] - nz[m1]);
    float den = 1.f + eb;
    float g1 = 1.f / den, g2 = eb / den;
    gating[(size_t)t * EE + m1] = g1;
    gating[(size_t)t * EE + m2] = g2;
    sel_e[t * 2] = m1; sel_e[t * 2 + 1] = m2;
    sel_g[t * 2] = g1; sel_g[t * 2 + 1] = g2;
  }
}

// ---------------- histogram + exclusive scan (1 block)
__global__ __launch_bounds__(256) void hist_scan_kernel(
    const int* __restrict__ sel_e, int* __restrict__ counts,
    int* __restrict__ offsets, int* __restrict__ cursors) {
  __shared__ int hist[EE];
  int tid = threadIdx.x;
  if (tid < EE) hist[tid] = 0;
  __syncthreads();
  for (int i = tid; i < NASG; i += 256) atomicAdd(&hist[sel_e[i]], 1);
  __syncthreads();
  if (tid == 0) {
    int off = 0;
    for (int e = 0; e < EE; e++) {
      counts[e] = hist[e]; offsets[e] = off; cursors[e] = off; off += hist[e];
    }
  }
}

// ---------------- build per-expert token lists
__global__ __launch_bounds__(256) void build_lists_kernel(
    const int* __restrict__ sel_e, const float* __restrict__ sel_g,
    int* __restrict__ cursors, int* __restrict__ tok_list,
    float* __restrict__ gate_list) {
  int t = blockIdx.x * 256 + threadIdx.x;
  int lane = threadIdx.x & 63;
#pragma unroll
  for (int k = 0; k < TOPK; k++) {
    int e = sel_e[t * 2 + k];
    float g = sel_g[t * 2 + k];
    for (int ee = 0; ee < EE; ee++) {
      unsigned long long m = __ballot(e == ee);
      if (m) {
        int leader = __ffsll(m) - 1;
        int base = 0;
        if (lane == leader) base = atomicAdd(&cursors[ee], __popcll(m));
        base = __shfl(base, leader);
        if (e == ee) {
          int slot = base + __popcll(m & ((1ull << lane) - 1ull));
          tok_list[slot] = t;
          gate_list[slot] = g;
        }
      }
    }
  }
}

// ---------------- 256x256 / BK=64 / 8-wave / 8-phase grouped GEMM
// LDS swizzle: stored chunk c of row r holds global chunk c^(r&7) (16B chunks),
// realized as linear global_load_lds dest + inverse-swizzled per-lane global
// source (involution). Reads XOR the same pattern.
// vmcnt ledger (per wave, 2 loads per issue call):
//   steady tile t P4: outstanding B(t+1)4 A(t+1)4 B(t+2)4 =12 -> vmcnt(4)
//   completes B(t+1)+A(t+1), leaves B(t+2).
//   drain tile NT-2: only B(NT-1)4+A(NT-1)4 =8 outstanding -> must vmcnt(0)
//   (vmcnt(4) would leave A(NT-1) in flight while tile NT-1 reads it — the
//   round-2 race).
template<int KLEN, bool GATHER, bool EPI2>
__global__ __launch_bounds__(512, 2) void gemm8_kernel(
    const u16* __restrict__ A, const u16* __restrict__ Bm,
    const float* __restrict__ bias, const int* __restrict__ tok_list,
    const float* __restrict__ gate_list, const int* __restrict__ counts,
    const int* __restrict__ offsets, int Ncols,
    u16* __restrict__ OutBf, float* __restrict__ final_out,
    float* __restrict__ expert_out) {
  constexpr int NT = KLEN / 64;
  static_assert(KLEN % 64 == 0, "");
  int e = blockIdx.z;
  int cnt = counts[e];
  int rt = blockIdx.y;
  if (rt * 256 >= cnt) return;
  int off = offsets[e];
  int col0 = blockIdx.x * 256;

  __shared__ __attribute__((aligned(16))) char ldsc[131072];  // A 64K | B 64K

  int tid = threadIdx.x;
  int w = tid >> 6, l = tid & 63;
  int wm = w >> 2, wn = w & 3;            // 2 x 4 wave grid
  int fr = l & 15, hi = l >> 4;
  int kk16 = hi << 4;
  int xr = (fr & 7) << 4;

  int rl0 = w * 8 + (l >> 3);
  int slotE = ((l & 7) ^ ((l >> 3) & 7)) << 3;  // pre-swizzled 8-elem slot
  const u16* aptr[4];
  const u16* bptr[4];
#pragma unroll
  for (int i = 0; i < 4; i++) {
    int r = rt * 256 + rl0 + i * 64;
    if (GATHER) {
      int idx = min(off + r, NASG - 1);
      aptr[i] = A + (size_t)tok_list[idx] * KLEN + slotE;
    } else {
      aptr[i] = A + (size_t)(off + r) * KLEN + slotE;
    }
    bptr[i] = Bm + ((size_t)e * Ncols + col0 + rl0 + i * 64) * KLEN + slotE;
  }
  char* ldsA = ldsc;
  char* ldsB = ldsc + 65536;

  auto issueA = [&](int t, int h) {
    char* d = ldsA + (t & 1) * 32768 + h * 16384 + w * 1024;
    glds16(aptr[h * 2 + 0] + t * 64, d);
    glds16(aptr[h * 2 + 1] + t * 64, d + 8192);
  };
  auto issueB = [&](int t, int h) {
    char* d = ldsB + (t & 1) * 32768 + h * 16384 + w * 1024;
    glds16(bptr[h * 2 + 0] + t * 64, d);
    glds16(bptr[h * 2 + 1] + t * 64, d + 8192);
  };

  f32x4 acc[8][4];
#pragma unroll
  for (int m = 0; m < 8; m++)
#pragma unroll
    for (int n = 0; n < 4; n++) acc[m][n] = (f32x4){0.f, 0.f, 0.f, 0.f};
  bf16x8 aF[4][2], bF0[2][2], bF1[2][2];

  // prologue: tile0 fully + B of tile1; keep B(1) in flight
  issueB(0, 0); issueB(0, 1); issueA(0, 0); issueA(0, 1);
  if (NT > 1) { issueB(1, 0); issueB(1, 1); }
  VMCNT4();
  BAR();

  for (int t = 0; t < NT; t++) {
    int abase = (t & 1) * 32768;
    int bbase = 65536 + (t & 1) * 32768;
    // ---- P1: read A(mh0)+B(nh0); issue A0(t+1)
#pragma unroll
    for (int mm = 0; mm < 4; mm++)
#pragma unroll
      for (int ks = 0; ks < 2; ks++)
        aF[mm][ks] = *(const bf16x8*)(ldsc + abase + (wm * 128 + mm * 16 + fr) * 128 +
                                      ((ks * 64 + kk16) ^ xr));
#pragma unroll
    for (int nn = 0; nn < 2; nn++)
#pragma unroll
      for (int ks = 0; ks < 2; ks++)
        bF0[nn][ks] = *(const bf16x8*)(ldsc + bbase + (wn * 64 + nn * 16 + fr) * 128 +
                                       ((ks * 64 + kk16) ^ xr));
    if (t + 1 < NT) issueA(t + 1, 0);
    BAR();
    __builtin_amdgcn_s_setprio(1);
#pragma unroll
    for (int mm = 0; mm < 4; mm++)
#pragma unroll
      for (int nn = 0; nn < 2; nn++)
#pragma unroll
        for (int ks = 0; ks < 2; ks++)
          acc[mm][nn] = __builtin_amdgcn_mfma_f32_16x16x32_bf16(aF[mm][ks], bF0[nn][ks], acc[mm][nn], 0, 0, 0);
    __builtin_amdgcn_s_setprio(0);
    BAR();
    // ---- P2: read B(nh1); issue A1(t+1)
#pragma unroll
    for (int nn = 0; nn < 2; nn++)
#pragma unroll
      for (int ks = 0; ks < 2; ks++)
        bF1[nn][ks] = *(const bf16x8*)(ldsc + bbase + (wn * 64 + 32 + nn * 16 + fr) * 128 +
                                       ((ks * 64 + kk16) ^ xr));
    if (t + 1 < NT) issueA(t + 1, 1);
    BAR();
    __builtin_amdgcn_s_setprio(1);
#pragma unroll
    for (int mm = 0; mm < 4; mm++)
#pragma unroll
      for (int nn = 0; nn < 2; nn++)
#pragma unroll
        for (int ks = 0; ks < 2; ks++)
          acc[mm][2 + nn] = __builtin_amdgcn_mfma_f32_16x16x32_bf16(aF[mm][ks], bF1[nn][ks], acc[mm][2 + nn], 0, 0, 0);
    __builtin_amdgcn_s_setprio(0);
    BAR();
    // ---- P3: read A(mh1); issue B0(t+2)
#pragma unroll
    for (int mm = 0; mm < 4; mm++)
#pragma unroll
      for (int ks = 0; ks < 2; ks++)
        aF[mm][ks] = *(const bf16x8*)(ldsc + abase + (wm * 128 + 64 + mm * 16 + fr) * 128 +
                                      ((ks * 64 + kk16) ^ xr));
    if (t + 2 < NT) issueB(t + 2, 0);
    BAR();
    __builtin_amdgcn_s_setprio(1);
#pragma unroll
    for (int mm = 0; mm < 4; mm++)
#pragma unroll
      for (int nn = 0; nn < 2; nn++)
#pragma unroll
        for (int ks = 0; ks < 2; ks++)
          acc[4 + mm][nn] = __builtin_amdgcn_mfma_f32_16x16x32_bf16(aF[mm][ks], bF0[nn][ks], acc[4 + mm][nn], 0, 0, 0);
    __builtin_amdgcn_s_setprio(0);
    BAR();
    // ---- P4: issue B1(t+2); counted vmcnt in steady state, full drain at end
    if (t + 2 < NT) {
      issueB(t + 2, 1);
      VMCNT4();
    } else {
      VMCNT0();   // drain: tile NT-2 has only 8 outstanding; vmcnt(4) would
                  // leave A(NT-1) in flight while tile NT-1 reads it
    }
    BAR();
    __builtin_amdgcn_s_setprio(1);
#pragma unroll
    for (int mm = 0; mm < 4; mm++)
#pragma unroll
      for (int nn = 0; nn < 2; nn++)
#pragma unroll
        for (int ks = 0; ks < 2; ks++)
          acc[4 + mm][2 + nn] = __builtin_amdgcn_mfma_f32_16x16x32_bf16(aF[mm][ks], bF1[nn][ks], acc[4 + mm][2 + nn], 0, 0, 0);
    __builtin_amdgcn_s_setprio(0);
    BAR();
  }

  // ---- epilogue
  float biasN[4];
  int cN[4];
#pragma unroll
  for (int n = 0; n < 4; n++) {
    cN[n] = col0 + wn * 64 + (n >> 1) * 32 + (n & 1) * 16 + fr;
    biasN[n] = bias[e * Ncols + cN[n]];
  }
  if constexpr (!EPI2) {
#pragma unroll
    for (int m = 0; m < 8; m++) {
      int rb = rt * 256 + wm * 128 + (m >> 2) * 64 + (m & 3) * 16 + hi * 4;
#pragma unroll
      for (int j = 0; j < 4; j++) {
        int r = rb + j;
        if (r < cnt) {
#pragma unroll
          for (int n = 0; n < 4; n++) {
            float v = acc[m][n][j] + biasN[n];
            OutBf[(size_t)(off + r) * Ncols + cN[n]] = f2bf(fmaxf(v, 0.f));
          }
        }
      }
    }
  } else {
#pragma unroll
    for (int m = 0; m < 8; m++) {
      int rb = rt * 256 + wm * 128 + (m >> 2) * 64 + (m & 3) * 16 + hi * 4;
#pragma unroll
      for (int j = 0; j < 4; j++) {
        int r = rb + j;
        if (r < cnt) {
          int idx = off + r;
          int tok = tok_list[idx];
          float g = gate_list[idx];
          size_t erow = ((size_t)e * TKN + tok) * DD;
          size_t frow = (size_t)tok * DD;
#pragma unroll
          for (int n = 0; n < 4; n++) {
            float val = (acc[m][n][j] + biasN[n]) * g;
            expert_out[erow + cN[n]] = val;
            atomicAdd(&final_out[frow + cN[n]], val);
          }
        }
      }
    }
  }
}

extern "C" void kernel_launch(void* const* d_in, const int* in_sizes, int n_in,
                              void* d_out, int out_size, void* d_ws, size_t ws_size,
                              hipStream_t stream) {
  const float* x     = (const float*)d_in[0];
  const float* noise = (const float*)d_in[1];
  const float* Wg    = (const float*)d_in[2];
  const float* bg    = (const float*)d_in[3];
  const float* Wn    = (const float*)d_in[4];
  const float* bn    = (const float*)d_in[5];
  const float* W1    = (const float*)d_in[6];
  const float* b1    = (const float*)d_in[7];
  const float* W2    = (const float*)d_in[8];
  const float* b2    = (const float*)d_in[9];

  float* final_out  = (float*)d_out;
  float* expert_out = final_out + (size_t)TKN * DD;
  float* gating     = expert_out + (size_t)EE * TKN * DD;

  char* ws = (char*)d_ws;
  size_t o = 0;
  auto alloc = [&](size_t bytes) {
    char* p = ws + o;
    o += bytes;
    o = (o + 255) & ~(size_t)255;
    return p;
  };
  u16*   xb        = (u16*)alloc((size_t)TKN * DD * 2);
  u16*   w1t       = (u16*)alloc((size_t)EE * HH * DD * 2);        // [E][H][D]
  u16*   w2t       = (u16*)alloc((size_t)EE * DD * HH * 2);        // [E][D][H]
  u16*   hbuf      = (u16*)alloc(((size_t)NASG + 256) * HH * 2);   // +256 pad rows
  int*   tok_list  = (int*)alloc((size_t)NASG * 4);
  float* gate_list = (float*)alloc((size_t)NASG * 4);
  int*   sel_e     = (int*)alloc((size_t)NASG * 4);
  float* sel_g     = (float*)alloc((size_t)NASG * 4);
  int*   counts    = (int*)alloc(256);
  int*   offsets   = (int*)alloc(256);
  int*   cursors   = (int*)alloc(256);

  hipMemsetAsync(d_out, 0, (size_t)out_size * sizeof(float), stream);

  transpose_cvt_kernel<<<dim3(HH / 32, DD / 32, EE), dim3(32, 8), 0, stream>>>(W1, w1t, DD, HH);
  transpose_cvt_kernel<<<dim3(DD / 32, HH / 32, EE), dim3(32, 8), 0, stream>>>(W2, w2t, HH, DD);

  router_kernel<<<TKN, 256, 0, stream>>>(x, noise, Wg, bg, Wn, bn, gating, xb, sel_e, sel_g);
  hist_scan_kernel<<<1, 256, 0, stream>>>(sel_e, counts, offsets, cursors);
  build_lists_kernel<<<TKN / 256, 256, 0, stream>>>(sel_e, sel_g, cursors, tok_list, gate_list);

  // GEMM1: h = relu(x[tok] @ W1[e] + b1), K=1024, N=4096
  gemm8_kernel<DD, true, false><<<dim3(HH / 256, 64, EE), 512, 0, stream>>>(
      xb, w1t, b1, tok_list, nullptr, counts, offsets, HH, hbuf, nullptr, nullptr);
  // GEMM2: y = (h @ W2[e] + b2) * gate, K=4096, N=1024
  gemm8_kernel<HH, false, true><<<dim3(DD / 256, 64, EE), 512, 0, stream>>>(
      hbuf, w2t, b2, tok_list, gate_list, counts, offsets, DD, nullptr, final_out, expert_out);
}